// Round 5
// baseline (1205.899 us; speedup 1.0000x reference)
//
#include <hip/hip_runtime.h>
#include <hip/hip_fp16.h>
#include <stdint.h>

typedef __attribute__((ext_vector_type(4))) float     f32x4;
typedef __attribute__((ext_vector_type(8))) short     s16x8;
typedef __attribute__((ext_vector_type(8))) _Float16  f16x8;
typedef __attribute__((ext_vector_type(4))) uint32_t  u32x4;
typedef __attribute__((ext_vector_type(2))) uint32_t  u32x2;

#define SP 262144   // 64*64*64

__device__ __forceinline__ unsigned short f2h_bits(float f) {
  return __builtin_bit_cast(unsigned short, (_Float16)f);   // RNE
}
__device__ __forceinline__ float h2f(unsigned short s) {
  return (float)__builtin_bit_cast(_Float16, s);
}
__device__ __forceinline__ f16x8 as_h8(s16x8 v) { return __builtin_bit_cast(f16x8, v); }
__device__ __forceinline__ float gelu_f(float z) {
  // tanh-form GELU: |err| vs exact erf-GELU ~1e-3, killed by 1e-6 layer-scale
  float u = 0.7978845608028654f * fmaf(0.044715f * z, z * z, z);
  float e = __expf(2.f * u);
  float th = 1.f - __fdividef(2.f, e + 1.f);
  return 0.5f * z * (1.f + th);
}

// ---------------- prep: transpose weights to f16 ----------------
// w1 [96c][384e] -> w1T [384e][96c] ; w2 [384e][96c] -> w2T [96c][384e]
__global__ __launch_bounds__(256) void prep_weights(
    const float* __restrict__ w1, const float* __restrict__ w2,
    unsigned short* __restrict__ w1T, unsigned short* __restrict__ w2T) {
  int i = blockIdx.x * 256 + threadIdx.x;
  if (i < 96 * 384) {
    int c = i / 384, e = i % 384;
    w1T[e * 96 + c] = f2h_bits(w1[i]);
    int e2 = i / 96, c2 = i % 96;
    w2T[c2 * 384 + e2] = f2h_bits(w2[i]);
  }
}

// ---------------- depthwise 7x7x7 conv, fp16-packed, h-partitioned ----------------
// block = (b, c, d-oct of 8 planes). 256 thr: t>>2 = h (one row each), t&3 = w-seg of 16.
// Each thread accumulates ALL 8 d-planes as 4 half2 pairs (every wave active on every z).
// LDS plane: u32 = (x,x) half2, stride 80 dwords, XOR-swizzle bits2-3 (conflict-free b128).
// Output: fp8 e4m3 (HW v_cvt_pk_fp8_f32) -> ws footprint 50.5 MB total (was 96 MiB —
// suspected d_ws overrun was corrupting harness memory during timed replays).
__global__ __launch_bounds__(256) void conv_dw(
    const float* __restrict__ x, const float* __restrict__ cw,
    const float* __restrict__ cb, uint8_t* __restrict__ yc) {
  __shared__ uint32_t P[70 * 80];
  __shared__ uint32_t F2[8 * 49];
  int bid0 = blockIdx.x;
  // XCD-chunked swizzle: 1536 blocks = 8 XCD * 192 (bijective).
  int bid = (bid0 & 7) * 192 + (bid0 >> 3);
  int d0 = (bid & 7) * 8;
  int c  = (bid >> 3) % 96;
  int b  = (bid >> 3) / 96;
  int t = threadIdx.x;
  int h  = t >> 2;
  int w0 = (t & 3) * 16;

  const float* fw = cw + c * 343;
  for (int j = t; j < 392; j += 256) {
    int kd8 = j / 49, q = j - kd8 * 49;
    float lo = (kd8 <= 6) ? fw[kd8 * 49 + q] : 0.f;
    float hi = (kd8 >= 1) ? fw[(kd8 - 1) * 49 + q] : 0.f;
    F2[j] = (uint32_t)f2h_bits(lo) | ((uint32_t)f2h_bits(hi) << 16);
  }
  const float* xc = x + (size_t)(b * 96 + c) * SP;

  __half2 acc[4][16];                      // pair p -> planes (d0+2p, d0+2p+1)
  __half2 z2 = __float2half2_rn(0.f);
#pragma unroll
  for (int i = 0; i < 4; ++i)
#pragma unroll
    for (int j = 0; j < 16; ++j) acc[i][j] = z2;

  for (int z = d0 - 3; z <= d0 + 10; ++z) {
    if (z < 0 || z >= 64) continue;        // block-uniform
    const float* xp = xc + (size_t)z * 4096;
    for (int i = t; i < 70 * 80; i += 256) {
      int r = i / 80, cc = i - r * 80;
      float v = 0.f;
      if (r >= 3 && r < 67 && cc >= 3 && cc < 67)
        v = xp[(r - 3) * 64 + (cc - 3)];
      int X = ((r >> 2) & 3) << 2;
      P[r * 80 + (cc ^ X)] = __builtin_bit_cast(uint32_t, __float2half2_rn(v));
    }
    __syncthreads();
#pragma unroll
    for (int rr = 0; rr < 7; ++rr) {       // kh = rr; P row = h + rr
      int r = h + rr;
      int X = ((r >> 2) & 3) << 2;
      const uint32_t* Pr = P + r * 80;
      uint32_t row[24];
#pragma unroll
      for (int k = 0; k < 6; ++k) {
        u32x4 v = *(const u32x4*)(Pr + ((w0 + 4 * k) ^ X));
        row[4 * k] = v.x; row[4 * k + 1] = v.y; row[4 * k + 2] = v.z; row[4 * k + 3] = v.w;
      }
#pragma unroll
      for (int p = 0; p < 4; ++p) {
        int kd8 = z - d0 - 2 * p + 3;      // block-uniform validity
        if (kd8 >= 0 && kd8 <= 7) {
          uint32_t f7[7];
#pragma unroll
          for (int kw = 0; kw < 7; ++kw) f7[kw] = F2[kd8 * 49 + rr * 7 + kw];
#pragma unroll
          for (int kw = 0; kw < 7; ++kw) {
            __half2 fv = __builtin_bit_cast(__half2, f7[kw]);
#pragma unroll
            for (int wi = 0; wi < 16; ++wi) {
              __half2 xv = __builtin_bit_cast(__half2, row[wi + kw]);
              acc[p][wi] = __hfma2(xv, fv, acc[p][wi]);
            }
          }
        }
      }
    }
    __syncthreads();  // before next plane overwrites P
  }

  float bias = cb[c];
  uint8_t* ybase = yc + (size_t)(b * 96 + c) * SP;   // byte units (fp8)
#pragma unroll
  for (int p = 0; p < 4; ++p) {
    uint32_t lo4[4], hi4[4];
#pragma unroll
    for (int k = 0; k < 4; ++k) {
      float l0 = __low2float(acc[p][4 * k])      + bias;
      float l1 = __low2float(acc[p][4 * k + 1])  + bias;
      float l2 = __low2float(acc[p][4 * k + 2])  + bias;
      float l3 = __low2float(acc[p][4 * k + 3])  + bias;
      float g0 = __high2float(acc[p][4 * k])     + bias;
      float g1 = __high2float(acc[p][4 * k + 1]) + bias;
      float g2 = __high2float(acc[p][4 * k + 2]) + bias;
      float g3 = __high2float(acc[p][4 * k + 3]) + bias;
      uint32_t u = 0;
      u = __builtin_amdgcn_cvt_pk_fp8_f32(l0, l1, u, false);
      u = __builtin_amdgcn_cvt_pk_fp8_f32(l2, l3, u, true);
      lo4[k] = u;
      uint32_t v = 0;
      v = __builtin_amdgcn_cvt_pk_fp8_f32(g0, g1, v, false);
      v = __builtin_amdgcn_cvt_pk_fp8_f32(g2, g3, v, true);
      hi4[k] = v;
    }
    uint8_t* dst0 = ybase + (size_t)(d0 + 2 * p) * 4096     + h * 64 + w0;
    uint8_t* dst1 = ybase + (size_t)(d0 + 2 * p + 1) * 4096 + h * 64 + w0;
    u32x4 a0 = {lo4[0], lo4[1], lo4[2], lo4[3]};
    u32x4 b0 = {hi4[0], hi4[1], hi4[2], hi4[3]};
    *(u32x4*)dst0 = a0;     // 16 fp8 bytes, 16B-aligned (w0 mult 16)
    *(u32x4*)dst1 = b0;
  }
}

// ---------------- fused LN + MLP + scale + residual (f16 MFMA) ----------------
// block = one (b,d,h) row of 64 positions, 4 waves.
// GEMM1 (swapped): H^T = w1^T · A^T, wave wv owns e-slice [96wv, 96wv+96)
// GEMM2 (swapped): Y^T partial over same e-slice (wave-private H).
// LDS: A-tile + LN stats overlay H (A fully consumed into bfr1 regs before first H write,
// enforced by a barrier); Y overlays H after GEMM2 reads. 50176 B -> 3 blocks/CU.
__global__ __launch_bounds__(256) void mlp_fused(
    const uint8_t* __restrict__ yc, const float* __restrict__ x,
    const unsigned short* __restrict__ w1T, const unsigned short* __restrict__ w2T,
    const float* __restrict__ lg, const float* __restrict__ lb,
    const float* __restrict__ b1, const float* __restrict__ b2,
    const float* __restrict__ sc, float* __restrict__ out) {
  __shared__ __align__(16) unsigned char lds[50176];    // H 64x392 f16
  unsigned short* H_ = (unsigned short*)lds;
  unsigned short* A_ = (unsigned short*)lds;            // [64][106] f16, 13568 B (overlay)
  float* psum = (float*)(lds + 13568);                  // [4][64]
  float* psq  = (float*)(lds + 14592);                  // [4][64]
  float* mu_s = (float*)(lds + 15616);                  // [64]
  float* rs_s = (float*)(lds + 15872);                  // [64]
  float* Y_   = (float*)lds;                            // [96][65] f32, 24960 B (overlay)

  int bid = blockIdx.x;
  int h = bid & 63, dd = (bid >> 6) & 63, b = bid >> 12;
  int t = threadIdx.x;
  int wv = t >> 6, l = t & 63;
  int lm = l & 15, hg = l >> 4;
  int m = l;            // position owned in LN/epilogue phases
  int q = wv;           // channel quarter

  // ---- 1. load yc column (fp8 -> f32 via HW cvt) + stats partials ----
  const uint8_t* ycb = yc + (size_t)b * 96 * SP + (size_t)dd * 4096 + h * 64 + m;
  float vals[24];
  float s1 = 0.f, s2 = 0.f;
#pragma unroll
  for (int i = 0; i < 24; ++i) {
    int c = q * 24 + i;
    uint32_t byte = ycb[(size_t)c * SP];
    float v = __builtin_amdgcn_cvt_f32_fp8(byte, 0);
    vals[i] = v; s1 += v; s2 += v * v;
  }
  psum[q * 64 + m] = s1;
  psq[q * 64 + m]  = s2;
  __syncthreads();
  if (t < 64) {
    float a  = psum[t] + psum[64 + t] + psum[128 + t] + psum[192 + t];
    float bq = psq[t]  + psq[64 + t]  + psq[128 + t]  + psq[192 + t];
    float mu = a * (1.f / 96.f);
    float var = bq * (1.f / 96.f) - mu * mu;
    mu_s[t] = mu;
    rs_s[t] = rsqrtf(var + 1e-6f);
  }
  __syncthreads();
  // ---- 2. normalize -> A [64][106] f16 ----
  {
    float mu = mu_s[m], rs = rs_s[m];
#pragma unroll
    for (int i = 0; i < 12; ++i) {
      int c = q * 24 + 2 * i;
      float v0 = (vals[2 * i]     - mu) * rs * lg[c]     + lb[c];
      float v1 = (vals[2 * i + 1] - mu) * rs * lg[c + 1] + lb[c + 1];
      *(uint32_t*)(A_ + m * 106 + c) = (uint32_t)f2h_bits(v0) | ((uint32_t)f2h_bits(v1) << 16);
    }
  }
  __syncthreads();

  // ---- 3. GEMM1: load ALL A-fragments first (A dies), then barrier, then H writes ----
  s16x8 bfr1[4][3];
#pragma unroll
  for (int mt = 0; mt < 4; ++mt) {
    const uint32_t* ap0 = (const uint32_t*)A_ + 53 * (mt * 16 + lm);
#pragma unroll
    for (int kt = 0; kt < 3; ++kt) {
      const uint32_t* ap = ap0 + kt * 16 + hg * 4;
      u32x4 tmp; tmp.x = ap[0]; tmp.y = ap[1]; tmp.z = ap[2]; tmp.w = ap[3];
      bfr1[mt][kt] = __builtin_bit_cast(s16x8, tmp);
    }
  }
  __syncthreads();   // all waves done reading A before anyone writes H (same memory)

  const s16x8* w1f = (const s16x8*)(w1T + (size_t)(96 * wv + lm) * 96 + hg * 8);
#pragma unroll
  for (int et = 0; et < 6; ++et) {
    s16x8 af0 = w1f[et * 192], af1 = w1f[et * 192 + 4], af2 = w1f[et * 192 + 8];
    f32x4 zz = {0.f, 0.f, 0.f, 0.f};
    f32x4 a1[4] = {zz, zz, zz, zz};
#pragma unroll
    for (int mt = 0; mt < 4; ++mt) {
      a1[mt] = __builtin_amdgcn_mfma_f32_16x16x32_f16(as_h8(af0), as_h8(bfr1[mt][0]), a1[mt], 0, 0, 0);
      a1[mt] = __builtin_amdgcn_mfma_f32_16x16x32_f16(as_h8(af1), as_h8(bfr1[mt][1]), a1[mt], 0, 0, 0);
      a1[mt] = __builtin_amdgcn_mfma_f32_16x16x32_f16(as_h8(af2), as_h8(bfr1[mt][2]), a1[mt], 0, 0, 0);
    }
    int e0 = 96 * wv + et * 16 + hg * 4;
    f32x4 bb = *(const f32x4*)(b1 + e0);
#pragma unroll
    for (int mt = 0; mt < 4; ++mt) {
      float g0 = gelu_f(a1[mt][0] + bb[0]);
      float g1 = gelu_f(a1[mt][1] + bb[1]);
      float g2 = gelu_f(a1[mt][2] + bb[2]);
      float g3 = gelu_f(a1[mt][3] + bb[3]);
      u32x2 pk2;
      pk2.x = (uint32_t)f2h_bits(g0) | ((uint32_t)f2h_bits(g1) << 16);
      pk2.y = (uint32_t)f2h_bits(g2) | ((uint32_t)f2h_bits(g3) << 16);
      *(u32x2*)(H_ + (mt * 16 + lm) * 392 + e0) = pk2;
    }
  }
  __syncthreads();   // defensive: order H writes before H reads block-wide

  // ---- 4. GEMM2 over wave's K-slice ----
  s16x8 bfr2[4][3];
#pragma unroll
  for (int mt = 0; mt < 4; ++mt)
#pragma unroll
    for (int kt = 0; kt < 3; ++kt)
      bfr2[mt][kt] = *(const s16x8*)(H_ + (mt * 16 + lm) * 392 + 96 * wv + kt * 32 + hg * 8);

  f32x4 acc2[6][4];
  {
    f32x4 zz = {0.f, 0.f, 0.f, 0.f};
#pragma unroll
    for (int ct = 0; ct < 6; ++ct)
#pragma unroll
      for (int mt = 0; mt < 4; ++mt) acc2[ct][mt] = zz;
  }
  const s16x8* w2f = (const s16x8*)(w2T + (size_t)lm * 384 + 96 * wv + hg * 8);
#pragma unroll
  for (int ct = 0; ct < 6; ++ct) {
    s16x8 a20 = w2f[ct * 768], a21 = w2f[ct * 768 + 4], a22 = w2f[ct * 768 + 8];
#pragma unroll
    for (int mt = 0; mt < 4; ++mt) {
      acc2[ct][mt] = __builtin_amdgcn_mfma_f32_16x16x32_f16(as_h8(a20), as_h8(bfr2[mt][0]), acc2[ct][mt], 0, 0, 0);
      acc2[ct][mt] = __builtin_amdgcn_mfma_f32_16x16x32_f16(as_h8(a21), as_h8(bfr2[mt][1]), acc2[ct][mt], 0, 0, 0);
      acc2[ct][mt] = __builtin_amdgcn_mfma_f32_16x16x32_f16(as_h8(a22), as_h8(bfr2[mt][2]), acc2[ct][mt], 0, 0, 0);
    }
  }
  __syncthreads();  // all H reads done; Y overlays H

  // ---- 5. cross-wave K-reduction into Y[96][65] ----
#pragma unroll
  for (int s = 0; s < 4; ++s) {
#pragma unroll
    for (int mt = 0; mt < 4; ++mt) {
      if (((mt - wv) & 3) == s) {  // wave-uniform
#pragma unroll
        for (int ct = 0; ct < 6; ++ct) {
          int c0 = ct * 16 + hg * 4;
          int mm = mt * 16 + lm;
          f32x4 v = acc2[ct][mt];
          float* yp = Y_ + c0 * 65 + mm;
          if (s == 0) {
            f32x4 bb = *(const f32x4*)(b2 + c0);
            yp[0]   = v[0] + bb[0]; yp[65]  = v[1] + bb[1];
            yp[130] = v[2] + bb[2]; yp[195] = v[3] + bb[3];
          } else {
            yp[0] += v[0]; yp[65] += v[1]; yp[130] += v[2]; yp[195] += v[3];
          }
        }
      }
    }
    __syncthreads();
  }

  // ---- 6. epilogue: out = scale*Y + x ----
  {
    const float* xb = x + (size_t)b * 96 * SP + (size_t)dd * 4096 + h * 64 + m;
    float* ob = out + (size_t)b * 96 * SP + (size_t)dd * 4096 + h * 64 + m;
#pragma unroll
    for (int i = 0; i < 24; ++i) {
      int c = q * 24 + i;
      float yv = Y_[c * 65 + m];
      ob[(size_t)c * SP] = fmaf(sc[c], yv, xb[(size_t)c * SP]);
    }
  }
}

extern "C" void kernel_launch(void* const* d_in, const int* in_sizes, int n_in,
                              void* d_out, int out_size, void* d_ws, size_t ws_size,
                              hipStream_t stream) {
  const float* x  = (const float*)d_in[0];
  const float* cw = (const float*)d_in[1];
  const float* cb = (const float*)d_in[2];
  const float* lg = (const float*)d_in[3];
  const float* lb = (const float*)d_in[4];
  const float* w1 = (const float*)d_in[5];
  const float* b1 = (const float*)d_in[6];
  const float* w2 = (const float*)d_in[7];
  const float* b2 = (const float*)d_in[8];
  const float* sc = (const float*)d_in[9];
  float* out = (float*)d_out;

  // ws: w1T (73728 B) | w2T (73728 B) | yc fp8 (50331648 B) = 50,479,104 B total
  unsigned short* w1T = (unsigned short*)d_ws;
  unsigned short* w2T = w1T + 96 * 384;
  uint8_t*        yc  = (uint8_t*)(w2T + 96 * 384);

  hipLaunchKernelGGL(prep_weights, dim3(144), dim3(256), 0, stream, w1, w2, w1T, w2T);
  hipLaunchKernelGGL(conv_dw, dim3(2 * 96 * 8), dim3(256), 0, stream, x, cw, cb, yc);
  hipLaunchKernelGGL(mlp_fused, dim3(8192), dim3(256), 0, stream, yc, x, w1T, w2T,
                     lg, lb, b1, b2, sc, out);
}